// Round 1
// baseline (373.028 us; speedup 1.0000x reference)
//
#include <hip/hip_runtime.h>
#include <hip/hip_bf16.h>

// SimpleAttention fused block on MI355X (gfx950), bf16 MFMA pipeline.
// B=2, S=2048, D_MODEL=2048, H=16, DK=128.
//
// ws layout (bytes):          size
//  xb      [4096,2048] bf16    16M @ 0
//  wqkvb   [6144,2048] bf16    24M @ 16M
//  wob     [2048,2048] bf16     8M @ 40M
//  Qb  [B,H,S,128] bf16        16M @ 48M   (pre-rope from gemm, rope in place)
//  Kb  [B,H,S,128] bf16        16M @ 64M
//  Vt  [B,H,128,S] bf16        16M @ 80M
//  Ao  [B,S,2048]  bf16        16M @ 96M
//  ctab [2048,64] f32         512K @ 112M
//  stab [2048,64] f32         512K @ 113M
// total ~113.5 MB

typedef __bf16 bf16;
typedef __bf16 bf16x8 __attribute__((ext_vector_type(8)));
typedef float f32x4 __attribute__((ext_vector_type(4)));

#define DEV __device__ __forceinline__

DEV void gll16(const void* g, void* lds_base_wave_uniform) {
  // global -> LDS direct, 16B per lane; LDS dest = uniform base + lane*16
  __builtin_amdgcn_global_load_lds((const __attribute__((address_space(1))) void*)g,
                                   (__attribute__((address_space(3))) void*)lds_base_wave_uniform,
                                   16, 0, 0);
}

DEV f32x4 mfma16(bf16x8 a, bf16x8 b, f32x4 c) {
  return __builtin_amdgcn_mfma_f32_16x16x32_bf16(a, b, c, 0, 0, 0);
}

// ---------------- f32 -> bf16 convert ----------------
__global__ __launch_bounds__(256) void cvt_f32_bf16(const float* __restrict__ in,
                                                    bf16* __restrict__ out, int n) {
  int i = (blockIdx.x * 256 + threadIdx.x) << 3;
  if (i >= n) return;
  float4 a = *(const float4*)(in + i);
  float4 b = *(const float4*)(in + i + 4);
  bf16x8 o;
  o[0] = (bf16)a.x; o[1] = (bf16)a.y; o[2] = (bf16)a.z; o[3] = (bf16)a.w;
  o[4] = (bf16)b.x; o[5] = (bf16)b.y; o[6] = (bf16)b.z; o[7] = (bf16)b.w;
  *(bf16x8*)(out + i) = o;
}

// ---------------- rope tables ----------------
// freq[j] = 10000^(-j/63)  (linspace(0,1,64) inclusive!)
__global__ __launch_bounds__(256) void rope_table(float* __restrict__ ctab,
                                                  float* __restrict__ stab) {
  int id = blockIdx.x * 256 + threadIdx.x;  // 2048*64
  int s = id >> 6, j = id & 63;
  float freq = powf(10000.0f, -(float)j / 63.0f);
  float th = (float)s * freq;
  ctab[id] = cosf(th);
  stab[id] = sinf(th);
}

// ---------------- in-place rope on Qb (with scale) and Kb ----------------
// scale folds 1/sqrt(128) * log2(e) into Q so attention uses exp2.
__global__ __launch_bounds__(256) void rope_apply(bf16* __restrict__ Qb, bf16* __restrict__ Kb,
                                                  const float* __restrict__ ctab,
                                                  const float* __restrict__ stab) {
  const float QSCALE = 0.08838834764831845f * 1.4426950408889634f;
  int id = blockIdx.x * 256 + threadIdx.x;  // 2 * 32*2048*64
  const int half = 32 * 2048 * 64;
  bf16* P = (id < half) ? Qb : Kb;
  float scale = (id < half) ? QSCALE : 1.0f;
  int t = (id < half) ? id : id - half;
  int d2 = t & 63;
  int s = (t >> 6) & 2047;
  int bh = t >> 17;
  bf16* p = P + (((size_t)bh * 2048 + s) << 7);
  float x1 = (float)p[d2], x2 = (float)p[d2 + 64];
  float c = ctab[(s << 6) + d2], sn = stab[(s << 6) + d2];
  p[d2]      = (bf16)((x1 * c - x2 * sn) * scale);
  p[d2 + 64] = (bf16)((x1 * sn + x2 * c) * scale);
}

// ---------------- GEMM C = A * Bt^T, A[M,2048] Bt[N,2048] bf16 row-major ----------------
// 128x128 tile, BK=64, 4 waves (2x2), 16x16x32 MFMA, global_load_lds w=16,
// XOR-swizzled LDS (row-bit into 16B-block index) to avoid 16-way conflicts.
// MODE 0: scatter epilogue to Qb/Kb (bf16 [B,H,S,128]) and Vt ([B,H,128,S]).
// MODE 1: plain f32 C [M,2048].
template <int NT, int MODE>  // NT = N/128
__global__ __launch_bounds__(256) void gemm_bt(const bf16* __restrict__ A,
                                               const bf16* __restrict__ Bt,
                                               bf16* __restrict__ q_out, bf16* __restrict__ k_out,
                                               bf16* __restrict__ v_out,
                                               float* __restrict__ f_out) {
  constexpr int K = 2048;
  __shared__ bf16 As[128 * 64];
  __shared__ bf16 Bs[128 * 64];
  const int nwg = NT * 32;
  const int id = blockIdx.x;
  const int swz = (id & 7) * (nwg >> 3) + (id >> 3);  // XCD swizzle (nwg % 8 == 0)
  const int bx = swz % NT, by = swz / NT;
  const int m0 = by << 7, n0 = bx << 7;
  const int tid = threadIdx.x, w = tid >> 6, l = tid & 63;
  const int wr = w >> 1, wc = w & 1;

  f32x4 acc[4][4] = {};

#pragma unroll 1
  for (int kt = 0; kt < K / 64; ++kt) {
    __syncthreads();
    const int k0 = kt << 6;
#pragma unroll
    for (int i = 0; i < 4; ++i) {
      const int row = (w << 5) + (i << 3) + (l >> 3);  // 8 rows x 128B per inst
      const int blk = (l & 7) ^ (row & 7);
      gll16(A + (size_t)(m0 + row) * K + k0 + (blk << 3), (char*)As + (w << 12) + (i << 10));
      gll16(Bt + (size_t)(n0 + row) * K + k0 + (blk << 3), (char*)Bs + (w << 12) + (i << 10));
    }
    asm volatile("s_waitcnt vmcnt(0)" ::: "memory");
    __syncthreads();
#pragma unroll
    for (int ks = 0; ks < 2; ++ks) {
      bf16x8 a[4], b[4];
#pragma unroll
      for (int i = 0; i < 4; ++i) {
        const int ra = (wr << 6) + (i << 4) + (l & 15);
        a[i] = *(const bf16x8*)((const char*)As + ra * 128 +
                                (((ks << 6) + ((l >> 4) << 4)) ^ ((ra & 7) << 4)));
        const int rb = (wc << 6) + (i << 4) + (l & 15);
        b[i] = *(const bf16x8*)((const char*)Bs + rb * 128 +
                                (((ks << 6) + ((l >> 4) << 4)) ^ ((rb & 7) << 4)));
      }
#pragma unroll
      for (int i = 0; i < 4; ++i)
#pragma unroll
        for (int j = 0; j < 4; ++j)
          acc[i][j] = mfma16(a[i], b[j], acc[i][j]);
    }
  }

  if constexpr (MODE == 0) {
    const int which = n0 >> 11;        // 0=Q 1=K 2=V (head-aligned: tile is 1 head)
    const int h = (n0 >> 7) & 15;
    if (which < 2) {
      bf16* dst = which ? k_out : q_out;
#pragma unroll
      for (int i = 0; i < 4; ++i)
#pragma unroll
        for (int j = 0; j < 4; ++j)
#pragma unroll
          for (int r = 0; r < 4; ++r) {
            const int m = m0 + (wr << 6) + (i << 4) + ((l >> 4) << 2) + r;
            const int d = (wc << 6) + (j << 4) + (l & 15);
            const int b_ = m >> 11, s = m & 2047;
            dst[(((size_t)((b_ << 4) | h) * 2048 + s) << 7) + d] = (bf16)acc[i][j][r];
          }
    } else {
#pragma unroll
      for (int i = 0; i < 4; ++i)
#pragma unroll
        for (int j = 0; j < 4; ++j)
#pragma unroll
          for (int r = 0; r < 4; ++r) {
            const int m = m0 + (wr << 6) + (i << 4) + ((l >> 4) << 2) + r;
            const int d = (wc << 6) + (j << 4) + (l & 15);
            const int b_ = m >> 11, s = m & 2047;
            v_out[((size_t)((b_ << 4) | h) << 18) + ((size_t)d << 11) + s] = (bf16)acc[i][j][r];
          }
    }
  } else {
#pragma unroll
    for (int i = 0; i < 4; ++i)
#pragma unroll
      for (int j = 0; j < 4; ++j)
#pragma unroll
        for (int r = 0; r < 4; ++r) {
          const int m = m0 + (wr << 6) + (i << 4) + ((l >> 4) << 2) + r;
          const int n = n0 + (wc << 6) + (j << 4) + (l & 15);
          f_out[(size_t)m * 2048 + n] = acc[i][j][r];
        }
  }
}

// ---------------- causal flash attention ----------------
// grid 512 = B*H*16 q-tiles; qt flipped for second half to balance causal triangle.
// block: 4 waves; QB=128 (32 q-rows/wave), KB=64, DK=128.
// Q pre-scaled by 1/sqrt(dk)*log2e -> exp2 softmax.
__global__ __launch_bounds__(256) void attn_kernel(const bf16* __restrict__ Qb,
                                                   const bf16* __restrict__ Kb,
                                                   const bf16* __restrict__ Vt,
                                                   bf16* __restrict__ Ao) {
  constexpr int S = 2048;
  __shared__ bf16 Ks[64 * 128];   // [kv][d], swizzled
  __shared__ bf16 Vs[128 * 64];   // [d][kv], swizzled
  __shared__ bf16 Ps[128 * 64];   // [q][kv], per-wave-private rows, swizzled
  const int idx = blockIdx.x;
  const int bh = idx >> 4;
  int qt = idx & 15;
  if (idx & 256) qt = 15 - qt;
  const int q0 = qt << 7;
  const int tid = threadIdx.x, w = tid >> 6, l = tid & 63;
  const bf16* Qp = Qb + ((size_t)bh << 18);
  const bf16* Kp = Kb + ((size_t)bh << 18);
  const bf16* Vp = Vt + ((size_t)bh << 18);

  bf16x8 qf[2][4];
#pragma unroll
  for (int rt = 0; rt < 2; ++rt)
#pragma unroll
    for (int kt = 0; kt < 4; ++kt)
      qf[rt][kt] = *(const bf16x8*)(Qp + ((size_t)(q0 + (w << 5) + (rt << 4) + (l & 15)) << 7) +
                                    (kt << 5) + ((l >> 4) << 3));

  f32x4 o[2][8] = {};
  float mrun[2][4], lrun[2][4];
#pragma unroll
  for (int rt = 0; rt < 2; ++rt)
#pragma unroll
    for (int r = 0; r < 4; ++r) { mrun[rt][r] = -3e38f; lrun[rt][r] = 0.f; }

  const int qmaxw = q0 + (w << 5) + 31;
  const int kv_end = q0 + 128;
#pragma unroll 1
  for (int kv0 = 0; kv0 < kv_end; kv0 += 64) {
    __syncthreads();
#pragma unroll
    for (int i = 0; i < 4; ++i) {
      const int rk = (w << 4) + (i << 2) + (l >> 4);  // 4 rows x 256B per inst
      gll16(Kp + ((size_t)(kv0 + rk) << 7) + (((l & 15) ^ (rk & 7)) << 3),
            (char*)Ks + (w << 12) + (i << 10));
      const int rv = (w << 5) + (i << 3) + (l >> 3);  // 8 rows x 128B per inst
      gll16(Vp + (size_t)rv * S + kv0 + (((l & 7) ^ (rv & 7)) << 3),
            (char*)Vs + (w << 12) + (i << 10));
    }
    asm volatile("s_waitcnt vmcnt(0)" ::: "memory");
    __syncthreads();
    if (kv0 <= qmaxw) {
      // ---- QK^T ----
      f32x4 sc[2][4] = {};
#pragma unroll
      for (int kt = 0; kt < 4; ++kt) {
        bf16x8 kb[4];
#pragma unroll
        for (int nt = 0; nt < 4; ++nt) {
          const int rk = (nt << 4) + (l & 15);
          kb[nt] = *(const bf16x8*)((const char*)Ks + (rk << 8) +
                                    (((kt << 6) + ((l >> 4) << 4)) ^ ((rk & 7) << 4)));
        }
#pragma unroll
        for (int rt = 0; rt < 2; ++rt)
#pragma unroll
          for (int nt = 0; nt < 4; ++nt)
            sc[rt][nt] = mfma16(qf[rt][kt], kb[nt], sc[rt][nt]);
      }
      // ---- causal mask (only diagonal tiles) ----
      if (kv0 + 64 > q0) {
#pragma unroll
        for (int rt = 0; rt < 2; ++rt)
#pragma unroll
          for (int nt = 0; nt < 4; ++nt)
#pragma unroll
            for (int r = 0; r < 4; ++r) {
              const int qg = q0 + (w << 5) + (rt << 4) + ((l >> 4) << 2) + r;
              const int kg = kv0 + (nt << 4) + (l & 15);
              if (kg > qg) sc[rt][nt][r] = -3e38f;
            }
      }
      // ---- online softmax (rows live in 16-lane groups) ----
      float alpha[2][4];
#pragma unroll
      for (int rt = 0; rt < 2; ++rt)
#pragma unroll
        for (int r = 0; r < 4; ++r) {
          float mx = fmaxf(fmaxf(sc[rt][0][r], sc[rt][1][r]), fmaxf(sc[rt][2][r], sc[rt][3][r]));
          mx = fmaxf(mx, __shfl_xor(mx, 1));
          mx = fmaxf(mx, __shfl_xor(mx, 2));
          mx = fmaxf(mx, __shfl_xor(mx, 4));
          mx = fmaxf(mx, __shfl_xor(mx, 8));
          const float mnew = fmaxf(mrun[rt][r], mx);
          alpha[rt][r] = exp2f(mrun[rt][r] - mnew);
          mrun[rt][r] = mnew;
        }
#pragma unroll
      for (int rt = 0; rt < 2; ++rt) {
        float psum[4] = {0.f, 0.f, 0.f, 0.f};
#pragma unroll
        for (int nt = 0; nt < 4; ++nt)
#pragma unroll
          for (int r = 0; r < 4; ++r) {
            const float p = exp2f(sc[rt][nt][r] - mrun[rt][r]);
            psum[r] += p;
            const int ql = (w << 5) + (rt << 4) + ((l >> 4) << 2) + r;
            const int kv = (nt << 4) + (l & 15);
            *(bf16*)((char*)Ps + (ql << 7) + ((kv << 1) ^ ((ql & 7) << 4))) = (bf16)p;
          }
#pragma unroll
        for (int r = 0; r < 4; ++r) lrun[rt][r] = lrun[rt][r] * alpha[rt][r] + psum[r];
      }
#pragma unroll
      for (int rt = 0; rt < 2; ++rt)
#pragma unroll
        for (int dt = 0; dt < 8; ++dt)
#pragma unroll
          for (int r = 0; r < 4; ++r) o[rt][dt][r] *= alpha[rt][r];
      asm volatile("" ::: "memory");  // keep P writes before P reads
      // ---- PV ----
#pragma unroll
      for (int ks = 0; ks < 2; ++ks) {
        bf16x8 pa[2], vb[8];
#pragma unroll
        for (int rt = 0; rt < 2; ++rt) {
          const int rq = (w << 5) + (rt << 4) + (l & 15);
          pa[rt] = *(const bf16x8*)((const char*)Ps + (rq << 7) +
                                    (((ks << 6) + ((l >> 4) << 4)) ^ ((rq & 7) << 4)));
        }
#pragma unroll
        for (int dt = 0; dt < 8; ++dt) {
          const int rd = (dt << 4) + (l & 15);
          vb[dt] = *(const bf16x8*)((const char*)Vs + (rd << 7) +
                                    (((ks << 6) + ((l >> 4) << 4)) ^ ((rd & 7) << 4)));
        }
#pragma unroll
        for (int rt = 0; rt < 2; ++rt)
#pragma unroll
          for (int dt = 0; dt < 8; ++dt) o[rt][dt] = mfma16(pa[rt], vb[dt], o[rt][dt]);
      }
    }
  }
  float rinv[2][4];
#pragma unroll
  for (int rt = 0; rt < 2; ++rt)
#pragma unroll
    for (int r = 0; r < 4; ++r) {
      float lv = lrun[rt][r];
      lv += __shfl_xor(lv, 1);
      lv += __shfl_xor(lv, 2);
      lv += __shfl_xor(lv, 4);
      lv += __shfl_xor(lv, 8);
      rinv[rt][r] = 1.0f / lv;
    }
  const int b = bh >> 4, h = bh & 15;
#pragma unroll
  for (int rt = 0; rt < 2; ++rt)
#pragma unroll
    for (int dt = 0; dt < 8; ++dt)
#pragma unroll
      for (int r = 0; r < 4; ++r) {
        const int sg = q0 + (w << 5) + (rt << 4) + ((l >> 4) << 2) + r;
        const int d = (dt << 4) + (l & 15);
        Ao[((size_t)(b * S + sg) << 11) + (h << 7) + d] = (bf16)(o[rt][dt][r] * rinv[rt][r]);
      }
}

// ---------------- launch ----------------
extern "C" void kernel_launch(void* const* d_in, const int* in_sizes, int n_in,
                              void* d_out, int out_size, void* d_ws, size_t ws_size,
                              hipStream_t stream) {
  const float* x = (const float*)d_in[0];      // [2,2048,2048]
  const float* w_qkv = (const float*)d_in[1];  // [6144,2048]
  const float* w_o = (const float*)d_in[2];    // [2048,2048]
  float* out = (float*)d_out;                  // [2,2048,2048] f32
  char* ws = (char*)d_ws;                      // needs ~114 MB

  bf16* xb    = (bf16*)(ws);
  bf16* wqkvb = (bf16*)(ws + (16ull << 20));
  bf16* wob   = (bf16*)(ws + (40ull << 20));
  bf16* Qb    = (bf16*)(ws + (48ull << 20));
  bf16* Kb    = (bf16*)(ws + (64ull << 20));
  bf16* Vt    = (bf16*)(ws + (80ull << 20));
  bf16* Ao    = (bf16*)(ws + (96ull << 20));
  float* ctab = (float*)(ws + (112ull << 20));
  float* stab = (float*)(ws + (113ull << 20));

  cvt_f32_bf16<<<4096, 256, 0, stream>>>(x, xb, 2 * 2048 * 2048);
  cvt_f32_bf16<<<6144, 256, 0, stream>>>(w_qkv, wqkvb, 6144 * 2048);
  cvt_f32_bf16<<<2048, 256, 0, stream>>>(w_o, wob, 2048 * 2048);
  rope_table<<<512, 256, 0, stream>>>(ctab, stab);
  gemm_bt<48, 0><<<1536, 256, 0, stream>>>(xb, wqkvb, Qb, Kb, Vt, nullptr);
  rope_apply<<<32768, 256, 0, stream>>>(Qb, Kb, ctab, stab);
  attn_kernel<<<512, 256, 0, stream>>>(Qb, Kb, Vt, Ao);
  gemm_bt<16, 1><<<512, 256, 0, stream>>>(Ao, wob, nullptr, nullptr, nullptr, out);
}

// Round 3
// 291.943 us; speedup vs baseline: 1.2777x; 1.2777x over previous
//
#include <hip/hip_runtime.h>
#include <hip/hip_bf16.h>

// SimpleAttention fused block on MI355X (gfx950), bf16 MFMA pipeline.
// B=2, S=2048, D_MODEL=2048, H=16, DK=128.
//
// R3: R2 swapped-operand 32x32 attention + FIXED causal-tile condition:
//   diagonal iff kv0+63 > wave's MIN q (was: max q -> missed masks for waves 2,3).
//
// ws layout (bytes):          size
//  xb      [4096,2048] bf16    16M @ 0
//  wqkvb   [6144,2048] bf16    24M @ 16M
//  wob     [2048,2048] bf16     8M @ 40M
//  Qb  [B,H,S,128] bf16        16M @ 48M   (pre-rope from gemm, rope in place)
//  Kb  [B,H,S,128] bf16        16M @ 64M
//  Vt  [B,H,128,S] bf16        16M @ 80M
//  Ao  [B,S,2048]  bf16        16M @ 96M
//  ctab [2048,64] f32         512K @ 112M
//  stab [2048,64] f32         512K @ 113M

typedef __bf16 bf16;
typedef __bf16 bf16x4 __attribute__((ext_vector_type(4)));
typedef __bf16 bf16x8 __attribute__((ext_vector_type(8)));
typedef float f32x4 __attribute__((ext_vector_type(4)));
typedef float f32x16 __attribute__((ext_vector_type(16)));
typedef int i32x4 __attribute__((ext_vector_type(4)));

#define DEV __device__ __forceinline__

DEV void gll16(const void* g, void* lds_base_wave_uniform) {
  __builtin_amdgcn_global_load_lds((const __attribute__((address_space(1))) void*)g,
                                   (__attribute__((address_space(3))) void*)lds_base_wave_uniform,
                                   16, 0, 0);
}

DEV f32x4 mfma16(bf16x8 a, bf16x8 b, f32x4 c) {
  return __builtin_amdgcn_mfma_f32_16x16x32_bf16(a, b, c, 0, 0, 0);
}
DEV f32x16 mfma32(bf16x8 a, bf16x8 b, f32x16 c) {
  return __builtin_amdgcn_mfma_f32_32x32x16_bf16(a, b, c, 0, 0, 0);
}

DEV int pack2(float x, float y) {
  union { bf16 h[2]; int i; } u;
  u.h[0] = (bf16)x; u.h[1] = (bf16)y;
  return u.i;
}

// ---------------- f32 -> bf16 convert ----------------
__global__ __launch_bounds__(256) void cvt_f32_bf16(const float* __restrict__ in,
                                                    bf16* __restrict__ out, int n) {
  int i = (blockIdx.x * 256 + threadIdx.x) << 3;
  if (i >= n) return;
  float4 a = *(const float4*)(in + i);
  float4 b = *(const float4*)(in + i + 4);
  bf16x8 o;
  o[0] = (bf16)a.x; o[1] = (bf16)a.y; o[2] = (bf16)a.z; o[3] = (bf16)a.w;
  o[4] = (bf16)b.x; o[5] = (bf16)b.y; o[6] = (bf16)b.z; o[7] = (bf16)b.w;
  *(bf16x8*)(out + i) = o;
}

// ---------------- rope tables ----------------
// freq[j] = 10000^(-j/63)  (linspace(0,1,64) inclusive!)
__global__ __launch_bounds__(256) void rope_table(float* __restrict__ ctab,
                                                  float* __restrict__ stab) {
  int id = blockIdx.x * 256 + threadIdx.x;  // 2048*64
  int s = id >> 6, j = id & 63;
  float freq = powf(10000.0f, -(float)j / 63.0f);
  float th = (float)s * freq;
  ctab[id] = cosf(th);
  stab[id] = sinf(th);
}

// ---------------- in-place rope on Qb (with scale) and Kb ----------------
__global__ __launch_bounds__(256) void rope_apply(bf16* __restrict__ Qb, bf16* __restrict__ Kb,
                                                  const float* __restrict__ ctab,
                                                  const float* __restrict__ stab) {
  const float QSCALE = 0.08838834764831845f * 1.4426950408889634f;
  int id = blockIdx.x * 256 + threadIdx.x;  // 2 * 32*2048*64
  const int half = 32 * 2048 * 64;
  bf16* P = (id < half) ? Qb : Kb;
  float scale = (id < half) ? QSCALE : 1.0f;
  int t = (id < half) ? id : id - half;
  int d2 = t & 63;
  int s = (t >> 6) & 2047;
  int bh = t >> 17;
  bf16* p = P + (((size_t)bh * 2048 + s) << 7);
  float x1 = (float)p[d2], x2 = (float)p[d2 + 64];
  float c = ctab[(s << 6) + d2], sn = stab[(s << 6) + d2];
  p[d2]      = (bf16)((x1 * c - x2 * sn) * scale);
  p[d2 + 64] = (bf16)((x1 * sn + x2 * c) * scale);
}

// ---------------- GEMM C = A * Bt^T, A[M,2048] Bt[N,2048] bf16 row-major ----------------
template <int NT, int MODE>  // NT = N/128
__global__ __launch_bounds__(256) void gemm_bt(const bf16* __restrict__ A,
                                               const bf16* __restrict__ Bt,
                                               bf16* __restrict__ q_out, bf16* __restrict__ k_out,
                                               bf16* __restrict__ v_out,
                                               float* __restrict__ f_out) {
  constexpr int K = 2048;
  __shared__ bf16 As[128 * 64];
  __shared__ bf16 Bs[128 * 64];
  const int nwg = NT * 32;
  const int id = blockIdx.x;
  const int swz = (id & 7) * (nwg >> 3) + (id >> 3);  // XCD swizzle (nwg % 8 == 0)
  const int bx = swz % NT, by = swz / NT;
  const int m0 = by << 7, n0 = bx << 7;
  const int tid = threadIdx.x, w = tid >> 6, l = tid & 63;
  const int wr = w >> 1, wc = w & 1;

  f32x4 acc[4][4] = {};

#pragma unroll 1
  for (int kt = 0; kt < K / 64; ++kt) {
    __syncthreads();
    const int k0 = kt << 6;
#pragma unroll
    for (int i = 0; i < 4; ++i) {
      const int row = (w << 5) + (i << 3) + (l >> 3);  // 8 rows x 128B per inst
      const int blk = (l & 7) ^ (row & 7);
      gll16(A + (size_t)(m0 + row) * K + k0 + (blk << 3), (char*)As + (w << 12) + (i << 10));
      gll16(Bt + (size_t)(n0 + row) * K + k0 + (blk << 3), (char*)Bs + (w << 12) + (i << 10));
    }
    asm volatile("s_waitcnt vmcnt(0)" ::: "memory");
    __syncthreads();
#pragma unroll
    for (int ks = 0; ks < 2; ++ks) {
      bf16x8 a[4], b[4];
#pragma unroll
      for (int i = 0; i < 4; ++i) {
        const int ra = (wr << 6) + (i << 4) + (l & 15);
        a[i] = *(const bf16x8*)((const char*)As + ra * 128 +
                                (((ks << 6) + ((l >> 4) << 4)) ^ ((ra & 7) << 4)));
        const int rb = (wc << 6) + (i << 4) + (l & 15);
        b[i] = *(const bf16x8*)((const char*)Bs + rb * 128 +
                                (((ks << 6) + ((l >> 4) << 4)) ^ ((rb & 7) << 4)));
      }
#pragma unroll
      for (int i = 0; i < 4; ++i)
#pragma unroll
        for (int j = 0; j < 4; ++j)
          acc[i][j] = mfma16(a[i], b[j], acc[i][j]);
    }
  }

  if constexpr (MODE == 0) {
    const int which = n0 >> 11;  // 0=Q 1=K 2=V (tile is within 1 head)
    const int h = (n0 >> 7) & 15;
    if (which < 2) {
      bf16* dst = which ? k_out : q_out;
#pragma unroll
      for (int i = 0; i < 4; ++i)
#pragma unroll
        for (int j = 0; j < 4; ++j)
#pragma unroll
          for (int r = 0; r < 4; ++r) {
            const int m = m0 + (wr << 6) + (i << 4) + ((l >> 4) << 2) + r;
            const int d = (wc << 6) + (j << 4) + (l & 15);
            const int b_ = m >> 11, s = m & 2047;
            dst[(((size_t)((b_ << 4) | h) * 2048 + s) << 7) + d] = (bf16)acc[i][j][r];
          }
    } else {
#pragma unroll
      for (int i = 0; i < 4; ++i)
#pragma unroll
        for (int j = 0; j < 4; ++j)
#pragma unroll
          for (int r = 0; r < 4; ++r) {
            const int m = m0 + (wr << 6) + (i << 4) + ((l >> 4) << 2) + r;
            const int d = (wc << 6) + (j << 4) + (l & 15);
            const int b_ = m >> 11, s = m & 2047;
            v_out[((size_t)((b_ << 4) | h) << 18) + ((size_t)d << 11) + s] = (bf16)acc[i][j][r];
          }
    }
  } else {
#pragma unroll
    for (int i = 0; i < 4; ++i)
#pragma unroll
      for (int j = 0; j < 4; ++j)
#pragma unroll
        for (int r = 0; r < 4; ++r) {
          const int m = m0 + (wr << 6) + (i << 4) + ((l >> 4) << 2) + r;
          const int n = n0 + (wc << 6) + (j << 4) + (l & 15);
          f_out[(size_t)m * 2048 + n] = acc[i][j][r];
        }
  }
}

// ---------------- causal flash attention, swapped-operand 32x32 ----------------
// grid 512 = B*H*16 q-tiles; 4 waves x QBLK=32 rows = QB 128; KVBLK=64.
// Q pre-scaled by 1/sqrt(dk)*log2e -> exp2 softmax.
// S^T = mfma32(Kfrag, Qfrag): lane q = l&31, kv(reg) = (r&3)+8*(r>>2)+4*(l>>5) per 32-blk.
// O^T = mfma32(Vtfrag, Pfrag): lane q = l&31, d(reg) = dt*32 + same pattern.
__global__ __launch_bounds__(256, 2) void attn_kernel(const bf16* __restrict__ Qb,
                                                      const bf16* __restrict__ Kb,
                                                      const bf16* __restrict__ Vt,
                                                      bf16* __restrict__ Ao) {
  constexpr int S = 2048;
  __shared__ bf16 Ks[64 * 128];  // [kv][d], 256B rows, swizzled
  __shared__ bf16 Vs[128 * 64];  // [d][kv], 128B rows, swizzled
  const int idx = blockIdx.x;
  const int bh = idx >> 4;
  int qt = idx & 15;
  if (idx & 256) qt = 15 - qt;  // balance causal triangle
  const int q0 = qt << 7;
  const int tid = threadIdx.x, w = tid >> 6, l = tid & 63;
  const int hi = l >> 5;  // 0 = lanes 0-31, 1 = lanes 32-63
  const bf16* Qp = Qb + ((size_t)bh << 18);
  const bf16* Kp = Kb + ((size_t)bh << 18);
  const bf16* Vp = Vt + ((size_t)bh << 18);

  // Q fragments: lane holds q-row q0+w*32+(l&31), k = kt*16 + hi*8 .. +8
  bf16x8 qf[8];
#pragma unroll
  for (int kt = 0; kt < 8; ++kt)
    qf[kt] = *(const bf16x8*)(Qp + ((size_t)(q0 + (w << 5) + (l & 31)) << 7) + (kt << 4) + (hi << 3));

  f32x16 o[4] = {};
  float mrun = -3e38f, lrun = 0.f;

  const int qminw = q0 + (w << 5);   // wave's first q row
  const int qmaxw = qminw + 31;      // wave's last q row
  const int kv_end = q0 + 128;
#pragma unroll 1
  for (int kv0 = 0; kv0 < kv_end; kv0 += 64) {
    __syncthreads();
#pragma unroll
    for (int i = 0; i < 4; ++i) {
      const int rk = (w << 4) + (i << 2) + (l >> 4);  // K: 4 rows x 256B per inst
      gll16(Kp + ((size_t)(kv0 + rk) << 7) + (((l & 15) ^ (rk & 7)) << 3),
            (char*)Ks + (w << 12) + (i << 10));
      const int rv = (w << 5) + (i << 3) + (l >> 3);  // V: 8 rows x 128B per inst
      gll16(Vp + (size_t)rv * S + kv0 + (((l & 7) ^ (rv & 7)) << 3),
            (char*)Vs + (w << 12) + (i << 10));
    }
    asm volatile("s_waitcnt vmcnt(0)" ::: "memory");
    __syncthreads();
    if (kv0 <= qmaxw) {
      // ---- S^T = K x Q^T : sc[nt] covers kv block nt*32, q = lane&31 ----
      f32x16 sc0 = {}, sc1 = {};
#pragma unroll
      for (int kt = 0; kt < 8; ++kt) {
        const int rk0 = l & 31;
        const int coff = ((kt << 5) + (hi << 4));
        bf16x8 k0 = *(const bf16x8*)((const char*)Ks + (rk0 << 8) + (coff ^ ((rk0 & 7) << 4)));
        bf16x8 k1 = *(const bf16x8*)((const char*)Ks + ((rk0 + 32) << 8) + (coff ^ ((rk0 & 7) << 4)));
        sc0 = mfma32(k0, qf[kt], sc0);
        sc1 = mfma32(k1, qf[kt], sc1);
      }
      // ---- causal mask: needed iff tile's max kv exceeds wave's MIN q ----
      if (kv0 + 63 > qminw) {
        const int qg = qminw + (l & 31);
#pragma unroll
        for (int r = 0; r < 16; ++r) {
          const int kvr = kv0 + (r & 3) + ((r >> 2) << 3) + (hi << 2);
          if (kvr > qg) sc0[r] = -3e38f;
          if (kvr + 32 > qg) sc1[r] = -3e38f;
        }
      }
      // ---- online softmax: row = lane-local 32 values + partner lane ----
      float mx = -3e38f;
#pragma unroll
      for (int r = 0; r < 16; ++r) mx = fmaxf(mx, fmaxf(sc0[r], sc1[r]));
      mx = fmaxf(mx, __shfl_xor(mx, 32));
      const float mnew = fmaxf(mrun, mx);
      if (!__all(mx <= mrun)) {  // defer-rescale: skip O pass when max unchanged
        const float alpha = exp2f(mrun - mnew);
        lrun *= alpha;
#pragma unroll
        for (int dt = 0; dt < 4; ++dt) o[dt] *= alpha;
      }
      mrun = mnew;
      float ps = 0.f;
#pragma unroll
      for (int r = 0; r < 16; ++r) {
        sc0[r] = exp2f(sc0[r] - mnew); ps += sc0[r];
        sc1[r] = exp2f(sc1[r] - mnew); ps += sc1[r];
      }
      ps += __shfl_xor(ps, 32);
      lrun += ps;
      // ---- O^T += V^T x P^T : P fragments assembled in-register ----
#pragma unroll
      for (int ks = 0; ks < 4; ++ks) {
        const f32x16& s = (ks & 2) ? sc1 : sc0;
        const int rb = (ks & 1) << 3;
        int pa_ = pack2(s[rb + 0], s[rb + 1]);
        int pb_ = pack2(s[rb + 2], s[rb + 3]);
        int pc_ = pack2(s[rb + 4], s[rb + 5]);
        int pd_ = pack2(s[rb + 6], s[rb + 7]);
        int sa = __shfl_xor(pa_, 32), sb = __shfl_xor(pb_, 32);
        int sc_ = __shfl_xor(pc_, 32), sd = __shfl_xor(pd_, 32);
        i32x4 pi;
        pi[0] = hi ? sc_ : pa_;
        pi[1] = hi ? sd : pb_;
        pi[2] = hi ? pc_ : sa;
        pi[3] = hi ? pd_ : sb;
        const bf16x8 pf = __builtin_bit_cast(bf16x8, pi);
#pragma unroll
        for (int dt = 0; dt < 4; ++dt) {
          const int rd = (dt << 5) + (l & 31);
          const bf16x8 vf = *(const bf16x8*)((const char*)Vs + (rd << 7) +
                                             (((ks << 5) + (hi << 4)) ^ ((rd & 7) << 4)));
          o[dt] = mfma32(vf, pf, o[dt]);
        }
      }
    }
  }
  // ---- epilogue: lane q = l&31, d = dt*32 + (r&3) + 8*(r>>2) + 4*hi ----
  const float rinv = 1.0f / lrun;
  const int b = bh >> 4, h = bh & 15;
  const int qg = q0 + (w << 5) + (l & 31);
  bf16* Arow = Ao + (((size_t)(b * S + qg)) << 11) + (h << 7);
#pragma unroll
  for (int dt = 0; dt < 4; ++dt)
#pragma unroll
    for (int g = 0; g < 4; ++g) {
      bf16x4 ov;
#pragma unroll
      for (int r = 0; r < 4; ++r) ov[r] = (bf16)(o[dt][(g << 2) + r] * rinv);
      *(bf16x4*)(Arow + (dt << 5) + (g << 3) + (hi << 2)) = ov;
    }
}

// ---------------- launch ----------------
extern "C" void kernel_launch(void* const* d_in, const int* in_sizes, int n_in,
                              void* d_out, int out_size, void* d_ws, size_t ws_size,
                              hipStream_t stream) {
  const float* x = (const float*)d_in[0];      // [2,2048,2048]
  const float* w_qkv = (const float*)d_in[1];  // [6144,2048]
  const float* w_o = (const float*)d_in[2];    // [2048,2048]
  float* out = (float*)d_out;                  // [2,2048,2048] f32
  char* ws = (char*)d_ws;

  bf16* xb    = (bf16*)(ws);
  bf16* wqkvb = (bf16*)(ws + (16ull << 20));
  bf16* wob   = (bf16*)(ws + (40ull << 20));
  bf16* Qb    = (bf16*)(ws + (48ull << 20));
  bf16* Kb    = (bf16*)(ws + (64ull << 20));
  bf16* Vt    = (bf16*)(ws + (80ull << 20));
  bf16* Ao    = (bf16*)(ws + (96ull << 20));
  float* ctab = (float*)(ws + (112ull << 20));
  float* stab = (float*)(ws + (113ull << 20));

  cvt_f32_bf16<<<4096, 256, 0, stream>>>(x, xb, 2 * 2048 * 2048);
  cvt_f32_bf16<<<6144, 256, 0, stream>>>(w_qkv, wqkvb, 6144 * 2048);
  cvt_f32_bf16<<<2048, 256, 0, stream>>>(w_o, wob, 2048 * 2048);
  rope_table<<<512, 256, 0, stream>>>(ctab, stab);
  gemm_bt<48, 0><<<1536, 256, 0, stream>>>(xb, wqkvb, Qb, Kb, Vt, nullptr);
  rope_apply<<<32768, 256, 0, stream>>>(Qb, Kb, ctab, stab);
  attn_kernel<<<512, 256, 0, stream>>>(Qb, Kb, Vt, Ao);
  gemm_bt<16, 1><<<512, 256, 0, stream>>>(Ao, wob, nullptr, nullptr, nullptr, out);
}